// Round 6
// baseline (1334.358 us; speedup 1.0000x reference)
//
#include <hip/hip_runtime.h>
#include <math.h>

#define S_LEN 100
#define NCAT  18
#define WSTR  520   // Wlds row stride in shorts
#define G_OFF 524288  // fp32 layer-0 gate partials: 3200 tiles * 16 KB = 50 MiB

typedef __attribute__((ext_vector_type(8)))  short  short8;
typedef __attribute__((ext_vector_type(16))) float  floatx16;

#define AT_LOADU(p)   __hip_atomic_load((p), __ATOMIC_RELAXED, __HIP_MEMORY_SCOPE_AGENT)
#define AT_STORE(p,v) __hip_atomic_store((p),(v), __ATOMIC_RELAXED, __HIP_MEMORY_SCOPE_AGENT)

// ws byte layout:
//   H0[lstm][buf]: bf16 [64 b][256 k] at (lstm*2+buf)*32768         (0..131071)
//   H1[lstm][buf]: same              at 131072 + (lstm*2+buf)*32768  (..262143)
//   flags: group g in {0,1}: 32 slots x 16 B at 262144 + g*512
//   G: layer-0 gate partials (bias baked in), permuted-row acc layout, at G_OFF.
// Permuted A-row map: tile row tr (within wave jt's 32-row tile) holds weight
// row R = (tr&3)*256 + wg*16 + jt*8 + (tr>>2)  => acc[r] = gate (r&3),
// dim wg*16 + jt*8 + 2*(r>>2) + half, batch bt*32+(lane&31). H storage is
// UNPERMUTED [b][dim]; a shfl_xor(32) interleave packs contiguous u64 stores.
// B fragments are loaded DIRECTLY from global h rows into registers (no LDS
// staging): lane bl, slice s reads u64s  h_row(bl)*64 + s*4 + half*2, +1.

struct Params {
  const int* ivu; const int* ivo;
  const float* lro; const float* lru;
  const float* VE;
  const float* W[4][2];
  const float* b0[4]; const float* b1[4];
  const float* roW; const float* rob;
  const float* ruW; const float* rub;
  float* ws; float* out;
};

__device__ __forceinline__ unsigned short f2bf(float f) {
  unsigned u = __builtin_bit_cast(unsigned, f);
  u += 0x7FFFu + ((u >> 16) & 1u);          // RNE
  return (unsigned short)(u >> 16);
}
__device__ __forceinline__ float bf2f(unsigned short h) {
  unsigned u = ((unsigned)h) << 16;
  return __builtin_bit_cast(float, u);
}
__device__ __forceinline__ unsigned long long packbf4(float4 v) {
  return (unsigned long long)f2bf(v.x)
       | ((unsigned long long)f2bf(v.y) << 16)
       | ((unsigned long long)f2bf(v.z) << 32)
       | ((unsigned long long)f2bf(v.w) << 48);
}
__device__ __forceinline__ float sigm(float x) {
  return __builtin_amdgcn_rcpf(1.f + __expf(-x));
}
__device__ __forceinline__ float tanh_f(float x) {  // graceful at +/-inf
  return 1.f - 2.f * __builtin_amdgcn_rcpf(1.f + __expf(2.f * x));
}

__global__ void init_k(unsigned* bar, float* out) {
  bar[threadIdx.x] = 0u;                    // 256 dwords
  if (threadIdx.x == 0) out[64] = 0.f;      // KL accumulator
}

// ---- Parallel precompute: G[inst][t][wg] = x_t @ Wih0^T + b0 + b1, stored in
// the permuted-row per-lane MFMA acc layout described above.
__global__ __launch_bounds__(256) void gate0_k(Params P) {
  const int blk = blockIdx.x;               // (inst*100 + t)*16 + wg
  const int inst = blk / 1600;
  const int rem = blk - inst * 1600;
  const int t = rem >> 4, wg = rem & 15;
  const int tid = threadIdx.x, lane = tid & 63, wave = tid >> 6;
  const int jt = wave >> 1, bt = wave & 1, half = lane >> 5;
  const int trow = lane & 31;
  const int R = (trow & 3) * 256 + wg * 16 + jt * 8 + (trow >> 2);
  const int b = bt * 32 + trow;
  const int* __restrict__ idxp = inst ? P.ivo : P.ivu;
  const float* __restrict__ wih = P.W[inst][0] + (size_t)R * 256;
  const float* __restrict__ vr = P.VE + (size_t)idxp[b * S_LEN + t] * 256;

  floatx16 acc;
  #pragma unroll
  for (int r = 0; r < 16; ++r) {
    const int Rr = (r & 3) * 256 + wg * 16 + jt * 8 + 2 * (r >> 2) + half;
    acc[r] = P.b0[inst][Rr] + P.b1[inst][Rr];
  }
  #pragma unroll
  for (int s = 0; s < 16; ++s) {
    float4 a0 = *(const float4*)(wih + s * 16 + half * 8);
    float4 a1 = *(const float4*)(wih + s * 16 + half * 8 + 4);
    float4 e0 = *(const float4*)(vr + s * 16 + half * 8);
    float4 e1 = *(const float4*)(vr + s * 16 + half * 8 + 4);
    union { unsigned long long q[2]; short8 v; } ua, ub;
    ua.q[0] = packbf4(a0); ua.q[1] = packbf4(a1);
    ub.q[0] = packbf4(e0); ub.q[1] = packbf4(e1);
    acc = __builtin_amdgcn_mfma_f32_32x32x16_bf16(ua.v, ub.v, acc, 0, 0, 0);
  }
  float* gd = (float*)((char*)P.ws + G_OFF) + (size_t)blk * 4096 + tid * 16;
  *(floatx16*)gd = acc;
}

// 64 WGs x 256 thr (4 waves). Role swizzle clusters each lstm's 32 WGs on 4
// XCDs. Per step: poll+bar, direct global->reg B loads, dual-chain MFMA,
// in-register activations (c in regs), shfl-interleave h store, drain bar+flag.
__global__ __launch_bounds__(256, 1) void lstm_all(Params P) {
  __shared__ short Wlds[64 * WSTR];    // 66.5 KB bf16 weights

  const int tid  = threadIdx.x;
  const int lane = tid & 63;
  const int wave = tid >> 6;            // 0..3
  const int rbk  = blockIdx.x;
  const int xcd  = rbk & 7, grpi = rbk >> 3;
  const int lstm = xcd >> 2;                        // XCDs 0-3: lstm0, 4-7: lstm1
  const int idx32 = grpi * 4 + (xcd & 3);           // 0..31
  const int layer = idx32 >> 4;
  const int wg    = idx32 & 15;
  const int inst  = layer * 2 + lstm;   // 0=vu-L0 1=vo-L0 2=vu-L1 3=vo-L1
  const int gb    = idx32;              // layer*16+wg

  char* wsb = (char*)P.ws;
  unsigned* arr = (unsigned*)(wsb + 262144) + lstm * 128;   // 32 slots x 4 dwords

  const int jt = wave >> 1, bt = wave & 1;
  const int half = lane >> 5;
  const int trow = lane & 31;
  const int bl   = bt * 32 + trow;

  // ---- stage weights -> LDS bf16, permuted row map (one time) ----
  {
    const int jrow = tid >> 2;          // 0..63 = jts*32 + tr
    const int q    = tid & 3;
    const int tr   = jrow & 31, jts = jrow >> 5;
    const int R    = (tr & 3) * 256 + wg * 16 + jts * 8 + (tr >> 2);
    const float* wih = P.W[inst][0] + (size_t)R * 256;
    const float* whh = P.W[inst][1] + (size_t)R * 256;
    short* dst = &Wlds[jrow * WSTR];
    if (layer || q < 2) {               // layer 0: only k<256 (Whh)
      #pragma unroll
      for (int k = q * 128; k < q * 128 + 128; k += 8) {
        const float* src = layer ? ((k < 256) ? (wih + k) : (whh + (k - 256)))
                                 : (whh + k);
        float4 v0 = *(const float4*)src;
        float4 v1 = *(const float4*)(src + 4);
        *(unsigned long long*)(dst + k)     = packbf4(v0);
        *(unsigned long long*)(dst + k + 4) = packbf4(v1);
      }
    }
  }
  float bias16[16];
  if (layer) {
    #pragma unroll
    for (int r = 0; r < 16; ++r) {
      const int Rr = (r & 3) * 256 + wg * 16 + jt * 8 + 2 * (r >> 2) + half;
      bias16[r] = P.b0[inst][Rr] + P.b1[inst][Rr];
    }
  }

  // ---- zero own group's H buffers: 128 KB over 32 WGs = 2 u64 per thread ----
  #pragma unroll
  for (int j = 0; j < 2; ++j) {
    const int gi = gb * 512 + tid * 2 + j;
    const int r = gi >> 12, off = gi & 4095;
    char* base = wsb + ((r < 2) ? (size_t)(lstm * 2 + r) * 32768
                                : 131072 + (size_t)(lstm * 2 + r - 2) * 32768);
    AT_STORE((unsigned long long*)base + off, 0ull);
  }
  __syncthreads();                       // vmcnt(0) drain
  if (tid == 0) AT_STORE(arr + gb * 4, 1u);

  const int arow_off = (jt * 32 + trow) * WSTR + half * 8;
  const int bro = bl * 64 + half * 2;    // u64 index of lane's slice-0 chunk
  const float* __restrict__ gregion = (const float*)(wsb + G_OFF);

  floatx16 gcur;
  if (layer == 0)                        // prefetch G tile for t=0
    gcur = *(const floatx16*)(gregion
             + (size_t)((lstm * 100) * 16 + wg) * 4096 + tid * 16);
  float c[4] = {0.f, 0.f, 0.f, 0.f};

  for (int t = 0; t <= S_LEN; ++t) {
    // ---- one-hop barrier: wave 0 polls all 32 group slots ----
    if (wave == 0) {
      const unsigned want = (unsigned)(t + 1);
      const unsigned* slot = arr + trow * 4;
      while (!__all(AT_LOADU(slot) >= want)) { }
    }
    __syncthreads();

    const bool active = (layer == 0) ? (t < S_LEN) : (t >= 1);
    if (active) {
      const int cur = t & 1, prv = (t + 1) & 1;

      // ---- direct global->reg B loads + dual-chain MFMA ----
      floatx16 acc, acc2;
      if (layer == 0) {
        const unsigned long long* hsrc =
            (const unsigned long long*)(wsb + (size_t)(lstm * 2 + prv) * 32768);
        unsigned long long v[32];
        #pragma unroll
        for (int s = 0; s < 16; ++s) {
          v[2 * s]     = AT_LOADU(hsrc + bro + s * 4);
          v[2 * s + 1] = AT_LOADU(hsrc + bro + s * 4 + 1);
        }
        acc = gcur;                       // Wih0 x_t + b, precomputed
        #pragma unroll
        for (int r = 0; r < 16; ++r) acc2[r] = 0.f;
        #pragma unroll
        for (int s = 0; s < 16; s += 2) {
          short8 a0 = *(const short8*)&Wlds[arow_off + s * 16];
          short8 a1 = *(const short8*)&Wlds[arow_off + (s + 1) * 16];
          union { unsigned long long q[2]; short8 v8; } ub0, ub1;
          ub0.q[0] = v[2 * s];     ub0.q[1] = v[2 * s + 1];
          ub1.q[0] = v[2 * s + 2]; ub1.q[1] = v[2 * s + 3];
          acc  = __builtin_amdgcn_mfma_f32_32x32x16_bf16(a0, ub0.v8, acc,  0, 0, 0);
          acc2 = __builtin_amdgcn_mfma_f32_32x32x16_bf16(a1, ub1.v8, acc2, 0, 0, 0);
        }
      } else {
        const unsigned long long* lo =
            (const unsigned long long*)(wsb + (size_t)(lstm * 2 + prv) * 32768);   // y0_{t-1}
        const unsigned long long* hi =
            (const unsigned long long*)(wsb + 131072 + (size_t)(lstm * 2 + cur) * 32768); // h1_{t-1}
        unsigned long long v[64];
        #pragma unroll
        for (int s = 0; s < 16; ++s) {
          v[2 * s]     = AT_LOADU(lo + bro + s * 4);
          v[2 * s + 1] = AT_LOADU(lo + bro + s * 4 + 1);
        }
        #pragma unroll
        for (int s = 0; s < 16; ++s) {
          v[32 + 2 * s] = AT_LOADU(hi + bro + s * 4);
          v[33 + 2 * s] = AT_LOADU(hi + bro + s * 4 + 1);
        }
        #pragma unroll
        for (int r = 0; r < 16; ++r) { acc[r] = bias16[r]; acc2[r] = 0.f; }
        #pragma unroll
        for (int s = 0; s < 32; s += 2) {
          short8 a0 = *(const short8*)&Wlds[arow_off + s * 16];
          short8 a1 = *(const short8*)&Wlds[arow_off + (s + 1) * 16];
          union { unsigned long long q[2]; short8 v8; } ub0, ub1;
          ub0.q[0] = v[2 * s];     ub0.q[1] = v[2 * s + 1];
          ub1.q[0] = v[2 * s + 2]; ub1.q[1] = v[2 * s + 3];
          acc  = __builtin_amdgcn_mfma_f32_32x32x16_bf16(a0, ub0.v8, acc,  0, 0, 0);
          acc2 = __builtin_amdgcn_mfma_f32_32x32x16_bf16(a1, ub1.v8, acc2, 0, 0, 0);
        }
      }
      #pragma unroll
      for (int r = 0; r < 16; ++r) acc[r] += acc2[r];

      // ---- in-register activations: lane owns 4 gates x 4 dims, b fixed ----
      unsigned long long own = 0ull;
      #pragma unroll
      for (int q = 0; q < 4; ++q) {
        const float ig = sigm(acc[4 * q + 0]);
        const float fg = sigm(acc[4 * q + 1]);
        const float gg = tanh_f(acc[4 * q + 2]);
        const float og = sigm(acc[4 * q + 3]);
        const float cc = fg * c[q] + ig * gg;
        c[q] = cc;
        own |= ((unsigned long long)f2bf(og * tanh_f(cc))) << (16 * q);
      }
      // own holds dims base+2q+half (base = wg*16+jt*8), batch bl. Interleave
      // with partner lane (half^1, same batch) to form contiguous u64.
      {
        const unsigned long long oth =
            (unsigned long long)__shfl_xor((long long)own, 32, 64);
        const unsigned long long A = half ? oth : own;   // even-dim holder
        const unsigned long long B = half ? own : oth;   // odd-dim holder
        const unsigned a32 = half ? (unsigned)(A >> 32) : (unsigned)A;
        const unsigned b32 = half ? (unsigned)(B >> 32) : (unsigned)B;
        const unsigned long long pack =
              (unsigned long long)(a32 & 0xFFFFu)
            | ((unsigned long long)(b32 & 0xFFFFu) << 16)
            | ((unsigned long long)(a32 >> 16) << 32)
            | ((unsigned long long)(b32 >> 16) << 48);
        unsigned long long* hout = (layer == 0)
            ? (unsigned long long*)(wsb + (size_t)(lstm * 2 + cur) * 32768)
            : (unsigned long long*)(wsb + 131072 + (size_t)(lstm * 2 + prv) * 32768);
        AT_STORE(hout + bl * 64 + wg * 4 + jt * 2 + half, pack);
      }
    }
    if (t < S_LEN) {
      __syncthreads();                   // vmcnt(0) drain: h stores IF-visible
      if (tid == 0) AT_STORE(arr + gb * 4, (unsigned)(t + 2));
    }
    // prefetch next step's G during the coming poll wait
    if (layer == 0 && t + 1 < S_LEN)
      gcur = *(const floatx16*)(gregion
               + (size_t)((lstm * 100 + t + 1) * 16 + wg) * 4096 + tid * 16);
  }
}

// head: 64 blocks (one per batch) x 64 threads
__global__ __launch_bounds__(64) void head_kernel(Params P) {
  __shared__ float enc[256];
  __shared__ float dec[NCAT];
  const int b = blockIdx.x, t = threadIdx.x;
  char* wsb = (char*)P.ws;
  const unsigned short* hvu = (const unsigned short*)(wsb + 131072 + 1 * 32768) + b * 256;
  const unsigned short* hvo = (const unsigned short*)(wsb + 131072 + 3 * 32768) + b * 256;

  for (int m = t; m < 256; m += 64) {
    float s = P.rob[m];
    for (int j = 0; j < NCAT; ++j) s = fmaf(P.lro[b * NCAT + j], P.roW[m * NCAT + j], s);
    enc[m] = fmaxf(s, 0.f);
  }
  __syncthreads();
  for (int n = 0; n < NCAT; ++n) {
    const float* __restrict__ wr = P.ruW + n * 768;
    float s = 0.f;
    for (int k = t; k < 256; k += 64) {
      s = fmaf(bf2f(hvu[k]), wr[k], s);
      s = fmaf(bf2f(hvo[k]), wr[256 + k], s);
      s = fmaf(enc[k],       wr[512 + k], s);
    }
    for (int off = 32; off; off >>= 1) s += __shfl_down(s, off, 64);
    if (t == 0) dec[n] = s + P.rub[n];
  }
  __syncthreads();
  if (t == 0) {
    float M = dec[0];
    for (int j = 1; j < NCAT; ++j) M = fmaxf(M, dec[j]);
    float Ssum = 0.f;
    for (int j = 0; j < NCAT; ++j) Ssum += expf(dec[j] - M);
    const float lse = M + logf(Ssum);
    float neg = 0.f, kl = 0.f;
    for (int j = 0; j < NCAT; ++j) {
      const float lp = dec[j] - lse;
      const float q  = P.lru[b * NCAT + j];
      neg -= q * lp;
      kl  += q * (logf(q) - lp);
    }
    P.out[b] = neg;
    atomicAdd(&P.out[64], kl * 1.4426950408889634f * (1.f / 64.f));
  }
}

extern "C" void kernel_launch(void* const* d_in, const int* in_sizes, int n_in,
                              void* d_out, int out_size, void* d_ws, size_t ws_size,
                              hipStream_t stream) {
  Params P;
  P.ivu = (const int*)d_in[0];
  P.ivo = (const int*)d_in[1];
  P.lro = (const float*)d_in[2];
  if (in_sizes[3] >= in_sizes[4]) { P.VE = (const float*)d_in[3]; P.lru = (const float*)d_in[4]; }
  else                            { P.VE = (const float*)d_in[4]; P.lru = (const float*)d_in[3]; }
  // inst: 0 = vu-L0, 1 = vo-L0, 2 = vu-L1, 3 = vo-L1
  P.W[0][0] = (const float*)d_in[5];  P.W[0][1] = (const float*)d_in[6];
  P.b0[0]   = (const float*)d_in[7];  P.b1[0]   = (const float*)d_in[8];
  P.W[2][0] = (const float*)d_in[9];  P.W[2][1] = (const float*)d_in[10];
  P.b0[2]   = (const float*)d_in[11]; P.b1[2]   = (const float*)d_in[12];
  P.W[1][0] = (const float*)d_in[13]; P.W[1][1] = (const float*)d_in[14];
  P.b0[1]   = (const float*)d_in[15]; P.b1[1]   = (const float*)d_in[16];
  P.W[3][0] = (const float*)d_in[17]; P.W[3][1] = (const float*)d_in[18];
  P.b0[3]   = (const float*)d_in[19]; P.b1[3]   = (const float*)d_in[20];
  P.roW = (const float*)d_in[21]; P.rob = (const float*)d_in[22];
  P.ruW = (const float*)d_in[23]; P.rub = (const float*)d_in[24];
  P.ws  = (float*)d_ws;
  P.out = (float*)d_out;

  unsigned* bar = (unsigned*)((char*)d_ws + 262144);
  init_k<<<1, 256, 0, stream>>>(bar, P.out);
  gate0_k<<<dim3(3200), dim3(256), 0, stream>>>(P);

  void* args[] = { &P };
  hipLaunchCooperativeKernel((void*)lstm_all, dim3(64), dim3(256), args, 0, stream);
  head_kernel<<<64, 64, 0, stream>>>(P);
}

// Round 7
// 728.714 us; speedup vs baseline: 1.8311x; 1.8311x over previous
//
#include <hip/hip_runtime.h>
#include <math.h>

#define S_LEN 100
#define NCAT  18
#define HS    516   // hstage row stride in shorts
#define WSTR  520   // Wlds row stride in shorts
#define G_OFF 524288  // fp32 layer-0 gate partials: 3200 tiles * 16 KB = 50 MiB

typedef __attribute__((ext_vector_type(8)))  short  short8;
typedef __attribute__((ext_vector_type(16))) float  floatx16;

#define AT_LOADU(p)   __hip_atomic_load((p), __ATOMIC_RELAXED, __HIP_MEMORY_SCOPE_AGENT)
#define AT_STORE(p,v) __hip_atomic_store((p),(v), __ATOMIC_RELAXED, __HIP_MEMORY_SCOPE_AGENT)

// ws byte layout:
//   H0[lstm][buf]: bf16 [64 b][256 k] at (lstm*2+buf)*32768         (0..131071)
//   H1[lstm][buf]: same              at 131072 + (lstm*2+buf)*32768  (..262143)
//   flags: group g in {0,1}: 32 slots x 16 B at 262144 + g*512
//   G: layer-0 gate partials (bias baked in), permuted-row acc layout, at G_OFF.
// Permuted A-row map: tile row tr (within wave jt's 32-row tile) holds weight
// row R = (tr&3)*256 + wg*16 + jt*8 + (tr>>2)  => acc[r] = gate (r&3),
// dim wg*16 + jt*8 + 2*(r>>2) + half, batch bt*32+(lane&31). H storage is
// UNPERMUTED [b][dim]; a shfl_xor(32) interleave packs contiguous u64 stores.

struct Params {
  const int* ivu; const int* ivo;
  const float* lro; const float* lru;
  const float* VE;
  const float* W[4][2];
  const float* b0[4]; const float* b1[4];
  const float* roW; const float* rob;
  const float* ruW; const float* rub;
  float* ws; float* out;
};

__device__ __forceinline__ unsigned short f2bf(float f) {
  unsigned u = __builtin_bit_cast(unsigned, f);
  u += 0x7FFFu + ((u >> 16) & 1u);          // RNE
  return (unsigned short)(u >> 16);
}
__device__ __forceinline__ float bf2f(unsigned short h) {
  unsigned u = ((unsigned)h) << 16;
  return __builtin_bit_cast(float, u);
}
__device__ __forceinline__ unsigned long long packbf4(float4 v) {
  return (unsigned long long)f2bf(v.x)
       | ((unsigned long long)f2bf(v.y) << 16)
       | ((unsigned long long)f2bf(v.z) << 32)
       | ((unsigned long long)f2bf(v.w) << 48);
}
__device__ __forceinline__ float sigm(float x) {
  return __builtin_amdgcn_rcpf(1.f + __expf(-x));
}
__device__ __forceinline__ float tanh_f(float x) {  // graceful at +/-inf
  return 1.f - 2.f * __builtin_amdgcn_rcpf(1.f + __expf(2.f * x));
}

// ---- Parallel precompute: G[inst][t][wg] = x_t @ Wih0^T + b0 + b1, stored in
// the permuted-row per-lane MFMA acc layout. Block 3200 zeroes flags + out[64].
__global__ __launch_bounds__(256) void gate0_k(Params P) {
  const int tid = threadIdx.x;
  char* wsb = (char*)P.ws;
  if (blockIdx.x == 3200) {
    ((unsigned*)(wsb + 262144))[tid] = 0u;   // 256 dwords = both flag groups
    if (tid == 0) P.out[64] = 0.f;           // KL accumulator
    return;
  }
  const int blk = blockIdx.x;               // (inst*100 + t)*16 + wg
  const int inst = blk / 1600;
  const int rem = blk - inst * 1600;
  const int t = rem >> 4, wg = rem & 15;
  const int lane = tid & 63, wave = tid >> 6;
  const int jt = wave >> 1, bt = wave & 1, half = lane >> 5;
  const int trow = lane & 31;
  const int R = (trow & 3) * 256 + wg * 16 + jt * 8 + (trow >> 2);
  const int b = bt * 32 + trow;
  const int* __restrict__ idxp = inst ? P.ivo : P.ivu;
  const float* __restrict__ wih = P.W[inst][0] + (size_t)R * 256;
  const float* __restrict__ vr = P.VE + (size_t)idxp[b * S_LEN + t] * 256;

  floatx16 acc;
  #pragma unroll
  for (int r = 0; r < 16; ++r) {
    const int Rr = (r & 3) * 256 + wg * 16 + jt * 8 + 2 * (r >> 2) + half;
    acc[r] = P.b0[inst][Rr] + P.b1[inst][Rr];
  }
  #pragma unroll
  for (int s = 0; s < 16; ++s) {
    float4 a0 = *(const float4*)(wih + s * 16 + half * 8);
    float4 a1 = *(const float4*)(wih + s * 16 + half * 8 + 4);
    float4 e0 = *(const float4*)(vr + s * 16 + half * 8);
    float4 e1 = *(const float4*)(vr + s * 16 + half * 8 + 4);
    union { unsigned long long q[2]; short8 v; } ua, ub;
    ua.q[0] = packbf4(a0); ua.q[1] = packbf4(a1);
    ub.q[0] = packbf4(e0); ub.q[1] = packbf4(e1);
    acc = __builtin_amdgcn_mfma_f32_32x32x16_bf16(ua.v, ub.v, acc, 0, 0, 0);
  }
  float* gd = (float*)((char*)P.ws + G_OFF) + (size_t)blk * 4096 + tid * 16;
  *(floatx16*)gd = acc;
}

// 64 WGs x 256 thr (4 waves). Role swizzle clusters each lstm's 32 WGs on 4
// XCDs. Per step: poll+bar, stage hstage + bar, dual-chain MFMA, in-register
// activations (c in regs), shfl-interleave h store, drain bar + flag.
// Plain launch (64 blocks <= 256 CUs at 1 block/CU => co-resident).
__global__ __launch_bounds__(256, 1) void lstm_all(Params P) {
  __shared__ short          Wlds[64 * WSTR];    // 66.5 KB bf16 weights
  __shared__ unsigned short hstage[64 * HS];    // 64.5 KB x_t bf16 [b][k]

  const int tid  = threadIdx.x;
  const int lane = tid & 63;
  const int wave = tid >> 6;            // 0..3
  const int rbk  = blockIdx.x;
  const int xcd  = rbk & 7, grpi = rbk >> 3;
  const int lstm = xcd >> 2;                        // XCDs 0-3: lstm0, 4-7: lstm1
  const int idx32 = grpi * 4 + (xcd & 3);           // 0..31
  const int layer = idx32 >> 4;
  const int wg    = idx32 & 15;
  const int inst  = layer * 2 + lstm;   // 0=vu-L0 1=vo-L0 2=vu-L1 3=vo-L1
  const int gb    = idx32;              // layer*16+wg

  char* wsb = (char*)P.ws;
  unsigned* arr = (unsigned*)(wsb + 262144) + lstm * 128;   // 32 slots x 4 dwords

  const int jt = wave >> 1, bt = wave & 1;
  const int half = lane >> 5;
  const int trow = lane & 31;
  const int bl   = bt * 32 + trow;

  // ---- stage weights -> LDS bf16, permuted row map (one time) ----
  {
    const int jrow = tid >> 2;          // 0..63 = jts*32 + tr
    const int q    = tid & 3;
    const int tr   = jrow & 31, jts = jrow >> 5;
    const int R    = (tr & 3) * 256 + wg * 16 + jts * 8 + (tr >> 2);
    const float* wih = P.W[inst][0] + (size_t)R * 256;
    const float* whh = P.W[inst][1] + (size_t)R * 256;
    short* dst = &Wlds[jrow * WSTR];
    if (layer || q < 2) {               // layer 0: only k<256 (Whh)
      #pragma unroll
      for (int k = q * 128; k < q * 128 + 128; k += 8) {
        const float* src = layer ? ((k < 256) ? (wih + k) : (whh + (k - 256)))
                                 : (whh + k);
        float4 v0 = *(const float4*)src;
        float4 v1 = *(const float4*)(src + 4);
        *(unsigned long long*)(dst + k)     = packbf4(v0);
        *(unsigned long long*)(dst + k + 4) = packbf4(v1);
      }
    }
  }
  float bias16[16];
  if (layer) {
    #pragma unroll
    for (int r = 0; r < 16; ++r) {
      const int Rr = (r & 3) * 256 + wg * 16 + jt * 8 + 2 * (r >> 2) + half;
      bias16[r] = P.b0[inst][Rr] + P.b1[inst][Rr];
    }
  }

  // ---- zero own group's H buffers: 128 KB over 32 WGs = 2 u64 per thread ----
  #pragma unroll
  for (int j = 0; j < 2; ++j) {
    const int gi = gb * 512 + tid * 2 + j;
    const int r = gi >> 12, off = gi & 4095;
    char* base = wsb + ((r < 2) ? (size_t)(lstm * 2 + r) * 32768
                                : 131072 + (size_t)(lstm * 2 + r - 2) * 32768);
    AT_STORE((unsigned long long*)base + off, 0ull);
  }
  __syncthreads();                       // vmcnt(0) drain
  if (tid == 0) AT_STORE(arr + gb * 4, 1u);

  const int arow_off = (jt * 32 + trow) * WSTR + half * 8;
  const int brow_off = bl * HS + half * 8;
  const float* __restrict__ gregion = (const float*)(wsb + G_OFF);

  floatx16 gcur;
  if (layer == 0)                        // prefetch G tile for t=0
    gcur = *(const floatx16*)(gregion
             + (size_t)((lstm * 100) * 16 + wg) * 4096 + tid * 16);
  float c[4] = {0.f, 0.f, 0.f, 0.f};

  for (int t = 0; t <= S_LEN; ++t) {
    // ---- one-hop barrier: wave 0 polls all 32 group slots ----
    if (wave == 0) {
      const unsigned want = (unsigned)(t + 1);
      const unsigned* slot = arr + trow * 4;
      while (!__all(AT_LOADU(slot) >= want)) { }
    }
    __syncthreads();

    const bool active = (layer == 0) ? (t < S_LEN) : (t >= 1);
    if (active) {
      const int cur = t & 1, prv = (t + 1) & 1;

      // ---- stage x_t into LDS [b][HS] bf16 ----
      if (layer == 0) {
        const unsigned long long* s64 =
            (const unsigned long long*)(wsb + (size_t)(lstm * 2 + prv) * 32768);
        unsigned long long v[16];
        #pragma unroll
        for (int j = 0; j < 16; ++j) v[j] = AT_LOADU(s64 + tid + j * 256);
        #pragma unroll
        for (int j = 0; j < 16; ++j) {
          const int i = tid + j * 256, bb = i >> 6, kq = i & 63;
          *(unsigned long long*)&hstage[bb * HS + kq * 4] = v[j];
        }
      } else {
        const unsigned long long* lo =
            (const unsigned long long*)(wsb + (size_t)(lstm * 2 + prv) * 32768);   // y0_{t-1}
        const unsigned long long* hi =
            (const unsigned long long*)(wsb + 131072 + (size_t)(lstm * 2 + cur) * 32768); // h1_{t-1}
        unsigned long long v[32];                    // 32 loads in flight
        #pragma unroll
        for (int j = 0; j < 16; ++j) v[j]      = AT_LOADU(lo + tid + j * 256);
        #pragma unroll
        for (int j = 0; j < 16; ++j) v[16 + j] = AT_LOADU(hi + tid + j * 256);
        #pragma unroll
        for (int j = 0; j < 16; ++j) {
          const int i = tid + j * 256, bb = i >> 6, kq = i & 63;
          *(unsigned long long*)&hstage[bb * HS + kq * 4] = v[j];
        }
        #pragma unroll
        for (int j = 0; j < 16; ++j) {
          const int i = tid + j * 256, bb = i >> 6, kq = i & 63;
          *(unsigned long long*)&hstage[bb * HS + 256 + kq * 4] = v[16 + j];
        }
      }
      __syncthreads();

      // ---- MFMA: two independent accumulator chains, A and B from LDS ----
      floatx16 acc, acc2;
      if (layer == 0) {
        acc = gcur;                       // Wih0 x_t + b, precomputed
        #pragma unroll
        for (int r = 0; r < 16; ++r) acc2[r] = 0.f;
        #pragma unroll
        for (int s = 0; s < 16; s += 2) {
          short8 a0 = *(const short8*)&Wlds[arow_off + s * 16];
          short8 b0 = *(const short8*)&hstage[brow_off + s * 16];
          short8 a1 = *(const short8*)&Wlds[arow_off + (s + 1) * 16];
          short8 b1 = *(const short8*)&hstage[brow_off + (s + 1) * 16];
          acc  = __builtin_amdgcn_mfma_f32_32x32x16_bf16(a0, b0, acc,  0, 0, 0);
          acc2 = __builtin_amdgcn_mfma_f32_32x32x16_bf16(a1, b1, acc2, 0, 0, 0);
        }
      } else {
        #pragma unroll
        for (int r = 0; r < 16; ++r) { acc[r] = bias16[r]; acc2[r] = 0.f; }
        #pragma unroll
        for (int s = 0; s < 32; s += 2) {
          short8 a0 = *(const short8*)&Wlds[arow_off + s * 16];
          short8 b0 = *(const short8*)&hstage[brow_off + s * 16];
          short8 a1 = *(const short8*)&Wlds[arow_off + (s + 1) * 16];
          short8 b1 = *(const short8*)&hstage[brow_off + (s + 1) * 16];
          acc  = __builtin_amdgcn_mfma_f32_32x32x16_bf16(a0, b0, acc,  0, 0, 0);
          acc2 = __builtin_amdgcn_mfma_f32_32x32x16_bf16(a1, b1, acc2, 0, 0, 0);
        }
      }
      #pragma unroll
      for (int r = 0; r < 16; ++r) acc[r] += acc2[r];

      // ---- in-register activations: lane owns 4 gates x 4 dims, b fixed ----
      unsigned long long own = 0ull;
      #pragma unroll
      for (int q = 0; q < 4; ++q) {
        const float ig = sigm(acc[4 * q + 0]);
        const float fg = sigm(acc[4 * q + 1]);
        const float gg = tanh_f(acc[4 * q + 2]);
        const float og = sigm(acc[4 * q + 3]);
        const float cc = fg * c[q] + ig * gg;
        c[q] = cc;
        own |= ((unsigned long long)f2bf(og * tanh_f(cc))) << (16 * q);
      }
      // own holds dims base+2q+half (base = wg*16+jt*8), batch bl. Interleave
      // with partner lane (half^1, same batch) to form contiguous u64.
      {
        const unsigned long long oth =
            (unsigned long long)__shfl_xor((long long)own, 32, 64);
        const unsigned long long A = half ? oth : own;   // even-dim holder
        const unsigned long long B = half ? own : oth;   // odd-dim holder
        const unsigned a32 = half ? (unsigned)(A >> 32) : (unsigned)A;
        const unsigned b32 = half ? (unsigned)(B >> 32) : (unsigned)B;
        const unsigned long long pack =
              (unsigned long long)(a32 & 0xFFFFu)
            | ((unsigned long long)(b32 & 0xFFFFu) << 16)
            | ((unsigned long long)(a32 >> 16) << 32)
            | ((unsigned long long)(b32 >> 16) << 48);
        unsigned long long* hout = (layer == 0)
            ? (unsigned long long*)(wsb + (size_t)(lstm * 2 + cur) * 32768)
            : (unsigned long long*)(wsb + 131072 + (size_t)(lstm * 2 + prv) * 32768);
        AT_STORE(hout + bl * 64 + wg * 4 + jt * 2 + half, pack);
      }
    }
    if (t < S_LEN) {
      __syncthreads();                   // vmcnt(0) drain: h stores IF-visible
      if (tid == 0) AT_STORE(arr + gb * 4, (unsigned)(t + 2));
    }
    // prefetch next step's G during the coming poll wait
    if (layer == 0 && t + 1 < S_LEN)
      gcur = *(const floatx16*)(gregion
               + (size_t)((lstm * 100 + t + 1) * 16 + wg) * 4096 + tid * 16);
  }
}

// head: 64 blocks (one per batch) x 64 threads
__global__ __launch_bounds__(64) void head_kernel(Params P) {
  __shared__ float enc[256];
  __shared__ float dec[NCAT];
  const int b = blockIdx.x, t = threadIdx.x;
  char* wsb = (char*)P.ws;
  const unsigned short* hvu = (const unsigned short*)(wsb + 131072 + 1 * 32768) + b * 256;
  const unsigned short* hvo = (const unsigned short*)(wsb + 131072 + 3 * 32768) + b * 256;

  for (int m = t; m < 256; m += 64) {
    float s = P.rob[m];
    for (int j = 0; j < NCAT; ++j) s = fmaf(P.lro[b * NCAT + j], P.roW[m * NCAT + j], s);
    enc[m] = fmaxf(s, 0.f);
  }
  __syncthreads();
  for (int n = 0; n < NCAT; ++n) {
    const float* __restrict__ wr = P.ruW + n * 768;
    float s = 0.f;
    for (int k = t; k < 256; k += 64) {
      s = fmaf(bf2f(hvu[k]), wr[k], s);
      s = fmaf(bf2f(hvo[k]), wr[256 + k], s);
      s = fmaf(enc[k],       wr[512 + k], s);
    }
    for (int off = 32; off; off >>= 1) s += __shfl_down(s, off, 64);
    if (t == 0) dec[n] = s + P.rub[n];
  }
  __syncthreads();
  if (t == 0) {
    float M = dec[0];
    for (int j = 1; j < NCAT; ++j) M = fmaxf(M, dec[j]);
    float Ssum = 0.f;
    for (int j = 0; j < NCAT; ++j) Ssum += expf(dec[j] - M);
    const float lse = M + logf(Ssum);
    float neg = 0.f, kl = 0.f;
    for (int j = 0; j < NCAT; ++j) {
      const float lp = dec[j] - lse;
      const float q  = P.lru[b * NCAT + j];
      neg -= q * lp;
      kl  += q * (logf(q) - lp);
    }
    P.out[b] = neg;
    atomicAdd(&P.out[64], kl * 1.4426950408889634f * (1.f / 64.f));
  }
}

extern "C" void kernel_launch(void* const* d_in, const int* in_sizes, int n_in,
                              void* d_out, int out_size, void* d_ws, size_t ws_size,
                              hipStream_t stream) {
  Params P;
  P.ivu = (const int*)d_in[0];
  P.ivo = (const int*)d_in[1];
  P.lro = (const float*)d_in[2];
  if (in_sizes[3] >= in_sizes[4]) { P.VE = (const float*)d_in[3]; P.lru = (const float*)d_in[4]; }
  else                            { P.VE = (const float*)d_in[4]; P.lru = (const float*)d_in[3]; }
  // inst: 0 = vu-L0, 1 = vo-L0, 2 = vu-L1, 3 = vo-L1
  P.W[0][0] = (const float*)d_in[5];  P.W[0][1] = (const float*)d_in[6];
  P.b0[0]   = (const float*)d_in[7];  P.b1[0]   = (const float*)d_in[8];
  P.W[2][0] = (const float*)d_in[9];  P.W[2][1] = (const float*)d_in[10];
  P.b0[2]   = (const float*)d_in[11]; P.b1[2]   = (const float*)d_in[12];
  P.W[1][0] = (const float*)d_in[13]; P.W[1][1] = (const float*)d_in[14];
  P.b0[1]   = (const float*)d_in[15]; P.b1[1]   = (const float*)d_in[16];
  P.W[3][0] = (const float*)d_in[17]; P.W[3][1] = (const float*)d_in[18];
  P.b0[3]   = (const float*)d_in[19]; P.b1[3]   = (const float*)d_in[20];
  P.roW = (const float*)d_in[21]; P.rob = (const float*)d_in[22];
  P.ruW = (const float*)d_in[23]; P.rub = (const float*)d_in[24];
  P.ws  = (float*)d_ws;
  P.out = (float*)d_out;

  gate0_k<<<dim3(3201), dim3(256), 0, stream>>>(P);
  lstm_all<<<dim3(64), dim3(256), 0, stream>>>(P);
  head_kernel<<<dim3(64), dim3(64), 0, stream>>>(P);
}

// Round 8
// 635.776 us; speedup vs baseline: 2.0988x; 1.1462x over previous
//
#include <hip/hip_runtime.h>
#include <math.h>

#define S_LEN 100
#define NCAT  18
#define HS    516   // hstage row stride in shorts
#define WSTR  520   // Wlds row stride in shorts
#define FLG_OFF  262144   // 32 slots x 16 B per lstm group (1 KB total)
#define GFLG_OFF 263168   // 3200 u32 per-tile ready flags (12.8 KB)
#define G_OFF    524288   // fp32 layer-0 gate partials: 3200 tiles * 16 KB

typedef __attribute__((ext_vector_type(8)))  short  short8;
typedef __attribute__((ext_vector_type(16))) float  floatx16;

#define AT_LOADU(p)   __hip_atomic_load((p), __ATOMIC_RELAXED, __HIP_MEMORY_SCOPE_AGENT)
#define AT_STORE(p,v) __hip_atomic_store((p),(v), __ATOMIC_RELAXED, __HIP_MEMORY_SCOPE_AGENT)

// ws byte layout:
//   H0[lstm][buf]: bf16 [64 b][256 k] at (lstm*2+buf)*32768         (0..131071)
//   H1[lstm][buf]: same              at 131072 + (lstm*2+buf)*32768  (..262143)
//   flags: FLG_OFF; G-tile flags: GFLG_OFF; G data: G_OFF.
// Fused grid: blocks 0..63 = lstm lockstep (1 CU each); blocks 64..3263 =
// gate0 tiles (t-major dispatch). Producer->consumer is 1:1 per tile via
// store -> vmcnt-drain -> flag (relaxed agent atomics), same as H exchange.
// Permuted A-row map: tile row tr holds weight row
// R = (tr&3)*256 + wg*16 + jt*8 + (tr>>2) => acc[r] = gate (r&3),
// dim wg*16 + jt*8 + 2*(r>>2) + half, batch bt*32+(lane&31). H storage is
// UNPERMUTED [b][dim]; a shfl_xor(32) interleave packs contiguous u64 stores.

struct Params {
  const int* ivu; const int* ivo;
  const float* lro; const float* lru;
  const float* VE;
  const float* W[4][2];
  const float* b0[4]; const float* b1[4];
  const float* roW; const float* rob;
  const float* ruW; const float* rub;
  float* ws; float* out;
};

__device__ __forceinline__ unsigned short f2bf(float f) {
  unsigned u = __builtin_bit_cast(unsigned, f);
  u += 0x7FFFu + ((u >> 16) & 1u);          // RNE
  return (unsigned short)(u >> 16);
}
__device__ __forceinline__ float bf2f(unsigned short h) {
  unsigned u = ((unsigned)h) << 16;
  return __builtin_bit_cast(float, u);
}
__device__ __forceinline__ unsigned long long packbf4(float4 v) {
  return (unsigned long long)f2bf(v.x)
       | ((unsigned long long)f2bf(v.y) << 16)
       | ((unsigned long long)f2bf(v.z) << 32)
       | ((unsigned long long)f2bf(v.w) << 48);
}
__device__ __forceinline__ float sigm(float x) {
  return __builtin_amdgcn_rcpf(1.f + __expf(-x));
}
__device__ __forceinline__ float tanh_f(float x) {  // graceful at +/-inf
  return 1.f - 2.f * __builtin_amdgcn_rcpf(1.f + __expf(2.f * x));
}

// agent-scope load of one G tile (16 floats/thread) published by a producer
__device__ __forceinline__ floatx16 load_gtile(const char* wsb, int idx, int tid) {
  const unsigned long long* gp =
      (const unsigned long long*)(wsb + G_OFF + (size_t)idx * 16384) + tid * 8;
  floatx16 g;
  #pragma unroll
  for (int j = 0; j < 8; ++j) {
    union { unsigned long long u; float f[2]; } cv;
    cv.u = AT_LOADU(gp + j);
    g[2 * j] = cv.f[0]; g[2 * j + 1] = cv.f[1];
  }
  return g;
}

// ---- gate0 tile: G[inst][t][wg] = x_t @ Wih0^T + b0 + b1 (permuted-row acc
// layout), published with per-tile ready flag.
__device__ __forceinline__ void gate0_body(const Params& P, int idx) {
  char* wsb = (char*)P.ws;
  const int t = idx >> 5;                 // t-major dispatch
  const int r = idx & 31;
  const int inst = r >> 4, wg = r & 15;
  const int blk = (inst * 100 + t) * 16 + wg;   // G storage index

  const int tid = threadIdx.x, lane = tid & 63, wave = tid >> 6;
  const int jt = wave >> 1, bt = wave & 1, half = lane >> 5;
  const int trow = lane & 31;
  const int R = (trow & 3) * 256 + wg * 16 + jt * 8 + (trow >> 2);
  const int b = bt * 32 + trow;
  const int* __restrict__ idxp = inst ? P.ivo : P.ivu;
  const float* __restrict__ wih = P.W[inst][0] + (size_t)R * 256;
  const float* __restrict__ vr = P.VE + (size_t)idxp[b * S_LEN + t] * 256;

  floatx16 acc;
  #pragma unroll
  for (int rr = 0; rr < 16; ++rr) {
    const int Rr = (rr & 3) * 256 + wg * 16 + jt * 8 + 2 * (rr >> 2) + half;
    acc[rr] = P.b0[inst][Rr] + P.b1[inst][Rr];
  }
  #pragma unroll
  for (int s = 0; s < 16; ++s) {
    float4 a0 = *(const float4*)(wih + s * 16 + half * 8);
    float4 a1 = *(const float4*)(wih + s * 16 + half * 8 + 4);
    float4 e0 = *(const float4*)(vr + s * 16 + half * 8);
    float4 e1 = *(const float4*)(vr + s * 16 + half * 8 + 4);
    union { unsigned long long q[2]; short8 v; } ua, ub;
    ua.q[0] = packbf4(a0); ua.q[1] = packbf4(a1);
    ub.q[0] = packbf4(e0); ub.q[1] = packbf4(e1);
    acc = __builtin_amdgcn_mfma_f32_32x32x16_bf16(ua.v, ub.v, acc, 0, 0, 0);
  }
  // publish: agent-scope data stores, drain, then flag
  unsigned long long* gd =
      (unsigned long long*)(wsb + G_OFF + (size_t)blk * 16384) + tid * 8;
  #pragma unroll
  for (int j = 0; j < 8; ++j) {
    union { float f[2]; unsigned long long u; } cv;
    cv.f[0] = acc[2 * j]; cv.f[1] = acc[2 * j + 1];
    AT_STORE(gd + j, cv.u);
  }
  __syncthreads();                        // vmcnt(0) drain
  if (tid == 0) AT_STORE((unsigned*)(wsb + GFLG_OFF) + blk, 1u);
}

// Fused kernel. Blocks 0..63: lstm lockstep (role swizzle clusters each lstm's
// 32 WGs on 4 XCDs). Blocks 64+: gate0 tiles.
__global__ __launch_bounds__(256, 1) void lstm_all(Params P) {
  __shared__ short          Wlds[64 * WSTR];    // 66.5 KB bf16 weights
  __shared__ unsigned short hstage[64 * HS];    // 64.5 KB x_t bf16 [b][k]

  if (blockIdx.x >= 64) { gate0_body(P, (int)blockIdx.x - 64); return; }

  const int tid  = threadIdx.x;
  const int lane = tid & 63;
  const int wave = tid >> 6;            // 0..3
  const int rbk  = blockIdx.x;
  const int xcd  = rbk & 7, grpi = rbk >> 3;
  const int lstm = xcd >> 2;                        // XCDs 0-3: lstm0, 4-7: lstm1
  const int idx32 = grpi * 4 + (xcd & 3);           // 0..31
  const int layer = idx32 >> 4;
  const int wg    = idx32 & 15;
  const int inst  = layer * 2 + lstm;   // 0=vu-L0 1=vo-L0 2=vu-L1 3=vo-L1
  const int gb    = idx32;              // layer*16+wg

  char* wsb = (char*)P.ws;
  unsigned* arr = (unsigned*)(wsb + FLG_OFF) + lstm * 128;   // 32 slots x 4 dwords

  const int jt = wave >> 1, bt = wave & 1;
  const int half = lane >> 5;
  const int trow = lane & 31;
  const int bl   = bt * 32 + trow;

  // ---- stage weights -> LDS bf16, permuted row map (one time) ----
  {
    const int jrow = tid >> 2;          // 0..63 = jts*32 + tr
    const int q    = tid & 3;
    const int tr   = jrow & 31, jts = jrow >> 5;
    const int R    = (tr & 3) * 256 + wg * 16 + jts * 8 + (tr >> 2);
    const float* wih = P.W[inst][0] + (size_t)R * 256;
    const float* whh = P.W[inst][1] + (size_t)R * 256;
    short* dst = &Wlds[jrow * WSTR];
    if (layer || q < 2) {               // layer 0: only k<256 (Whh)
      #pragma unroll
      for (int k = q * 128; k < q * 128 + 128; k += 8) {
        const float* src = layer ? ((k < 256) ? (wih + k) : (whh + (k - 256)))
                                 : (whh + k);
        float4 v0 = *(const float4*)src;
        float4 v1 = *(const float4*)(src + 4);
        *(unsigned long long*)(dst + k)     = packbf4(v0);
        *(unsigned long long*)(dst + k + 4) = packbf4(v1);
      }
    }
  }
  float bias16[16];
  if (layer) {
    #pragma unroll
    for (int r = 0; r < 16; ++r) {
      const int Rr = (r & 3) * 256 + wg * 16 + jt * 8 + 2 * (r >> 2) + half;
      bias16[r] = P.b0[inst][Rr] + P.b1[inst][Rr];
    }
  }

  // ---- zero own group's H buffers: 128 KB over 32 WGs = 2 u64 per thread ----
  #pragma unroll
  for (int j = 0; j < 2; ++j) {
    const int gi = gb * 512 + tid * 2 + j;
    const int r = gi >> 12, off = gi & 4095;
    char* base = wsb + ((r < 2) ? (size_t)(lstm * 2 + r) * 32768
                                : 131072 + (size_t)(lstm * 2 + r - 2) * 32768);
    AT_STORE((unsigned long long*)base + off, 0ull);
  }
  __syncthreads();                       // vmcnt(0) drain
  if (tid == 0) AT_STORE(arr + gb * 4, 1u);

  const int arow_off = (jt * 32 + trow) * WSTR + half * 8;
  const int brow_off = bl * HS + half * 8;
  const unsigned* __restrict__ gflags = (const unsigned*)(wsb + GFLG_OFF);

  floatx16 gcur;
  if (layer == 0) {                      // wait + load G tile for t=0
    const int gidx = (lstm * 100) * 16 + wg;
    while (AT_LOADU(gflags + gidx) == 0) { }
    gcur = load_gtile(wsb, gidx, tid);
  }
  float c[4] = {0.f, 0.f, 0.f, 0.f};

  for (int t = 0; t <= S_LEN; ++t) {
    // ---- one-hop barrier: wave 0 polls all 32 group slots ----
    if (wave == 0) {
      const unsigned want = (unsigned)(t + 1);
      const unsigned* slot = arr + trow * 4;
      while (!__all(AT_LOADU(slot) >= want)) { }
    }
    __syncthreads();

    const bool active = (layer == 0) ? (t < S_LEN) : (t >= 1);
    if (active) {
      const int cur = t & 1, prv = (t + 1) & 1;

      // ---- stage x_t into LDS [b][HS] bf16 ----
      if (layer == 0) {
        const unsigned long long* s64 =
            (const unsigned long long*)(wsb + (size_t)(lstm * 2 + prv) * 32768);
        unsigned long long v[16];
        #pragma unroll
        for (int j = 0; j < 16; ++j) v[j] = AT_LOADU(s64 + tid + j * 256);
        #pragma unroll
        for (int j = 0; j < 16; ++j) {
          const int i = tid + j * 256, bb = i >> 6, kq = i & 63;
          *(unsigned long long*)&hstage[bb * HS + kq * 4] = v[j];
        }
      } else {
        const unsigned long long* lo =
            (const unsigned long long*)(wsb + (size_t)(lstm * 2 + prv) * 32768);   // y0_{t-1}
        const unsigned long long* hi =
            (const unsigned long long*)(wsb + 131072 + (size_t)(lstm * 2 + cur) * 32768); // h1_{t-1}
        unsigned long long v[32];                    // 32 loads in flight
        #pragma unroll
        for (int j = 0; j < 16; ++j) v[j]      = AT_LOADU(lo + tid + j * 256);
        #pragma unroll
        for (int j = 0; j < 16; ++j) v[16 + j] = AT_LOADU(hi + tid + j * 256);
        #pragma unroll
        for (int j = 0; j < 16; ++j) {
          const int i = tid + j * 256, bb = i >> 6, kq = i & 63;
          *(unsigned long long*)&hstage[bb * HS + kq * 4] = v[j];
        }
        #pragma unroll
        for (int j = 0; j < 16; ++j) {
          const int i = tid + j * 256, bb = i >> 6, kq = i & 63;
          *(unsigned long long*)&hstage[bb * HS + 256 + kq * 4] = v[16 + j];
        }
      }
      __syncthreads();

      // ---- MFMA: two independent accumulator chains, A and B from LDS ----
      floatx16 acc, acc2;
      if (layer == 0) {
        acc = gcur;                       // Wih0 x_t + b, precomputed
        #pragma unroll
        for (int r = 0; r < 16; ++r) acc2[r] = 0.f;
        #pragma unroll
        for (int s = 0; s < 16; s += 2) {
          short8 a0 = *(const short8*)&Wlds[arow_off + s * 16];
          short8 b0 = *(const short8*)&hstage[brow_off + s * 16];
          short8 a1 = *(const short8*)&Wlds[arow_off + (s + 1) * 16];
          short8 b1 = *(const short8*)&hstage[brow_off + (s + 1) * 16];
          acc  = __builtin_amdgcn_mfma_f32_32x32x16_bf16(a0, b0, acc,  0, 0, 0);
          acc2 = __builtin_amdgcn_mfma_f32_32x32x16_bf16(a1, b1, acc2, 0, 0, 0);
        }
      } else {
        #pragma unroll
        for (int r = 0; r < 16; ++r) { acc[r] = bias16[r]; acc2[r] = 0.f; }
        #pragma unroll
        for (int s = 0; s < 32; s += 2) {
          short8 a0 = *(const short8*)&Wlds[arow_off + s * 16];
          short8 b0 = *(const short8*)&hstage[brow_off + s * 16];
          short8 a1 = *(const short8*)&Wlds[arow_off + (s + 1) * 16];
          short8 b1 = *(const short8*)&hstage[brow_off + (s + 1) * 16];
          acc  = __builtin_amdgcn_mfma_f32_32x32x16_bf16(a0, b0, acc,  0, 0, 0);
          acc2 = __builtin_amdgcn_mfma_f32_32x32x16_bf16(a1, b1, acc2, 0, 0, 0);
        }
      }
      #pragma unroll
      for (int r = 0; r < 16; ++r) acc[r] += acc2[r];

      // ---- in-register activations: lane owns 4 gates x 4 dims, b fixed ----
      unsigned long long own = 0ull;
      #pragma unroll
      for (int q = 0; q < 4; ++q) {
        const float ig = sigm(acc[4 * q + 0]);
        const float fg = sigm(acc[4 * q + 1]);
        const float gg = tanh_f(acc[4 * q + 2]);
        const float og = sigm(acc[4 * q + 3]);
        const float cc = fg * c[q] + ig * gg;
        c[q] = cc;
        own |= ((unsigned long long)f2bf(og * tanh_f(cc))) << (16 * q);
      }
      // own holds dims base+2q+half (base = wg*16+jt*8), batch bl. Interleave
      // with partner lane (half^1, same batch) to form contiguous u64.
      {
        const unsigned long long oth =
            (unsigned long long)__shfl_xor((long long)own, 32, 64);
        const unsigned long long A = half ? oth : own;   // even-dim holder
        const unsigned long long B = half ? own : oth;   // odd-dim holder
        const unsigned a32 = half ? (unsigned)(A >> 32) : (unsigned)A;
        const unsigned b32 = half ? (unsigned)(B >> 32) : (unsigned)B;
        const unsigned long long pack =
              (unsigned long long)(a32 & 0xFFFFu)
            | ((unsigned long long)(b32 & 0xFFFFu) << 16)
            | ((unsigned long long)(a32 >> 16) << 32)
            | ((unsigned long long)(b32 >> 16) << 48);
        unsigned long long* hout = (layer == 0)
            ? (unsigned long long*)(wsb + (size_t)(lstm * 2 + cur) * 32768)
            : (unsigned long long*)(wsb + 131072 + (size_t)(lstm * 2 + prv) * 32768);
        AT_STORE(hout + bl * 64 + wg * 4 + jt * 2 + half, pack);
      }
    }
    if (t < S_LEN) {
      __syncthreads();                   // vmcnt(0) drain: h stores IF-visible
      if (tid == 0) AT_STORE(arr + gb * 4, (unsigned)(t + 2));
    }
    // fetch next step's G after own flag store (a miss never delays peers)
    if (layer == 0 && t + 1 < S_LEN) {
      const int gidx = (lstm * 100 + t + 1) * 16 + wg;
      while (AT_LOADU(gflags + gidx) == 0) { }
      gcur = load_gtile(wsb, gidx, tid);
    }
  }
}

// head: 64 blocks (one per batch) x 64 threads
__global__ __launch_bounds__(64) void head_kernel(Params P) {
  __shared__ float enc[256];
  __shared__ float dec[NCAT];
  const int b = blockIdx.x, t = threadIdx.x;
  char* wsb = (char*)P.ws;
  const unsigned short* hvu = (const unsigned short*)(wsb + 131072 + 1 * 32768) + b * 256;
  const unsigned short* hvo = (const unsigned short*)(wsb + 131072 + 3 * 32768) + b * 256;

  for (int m = t; m < 256; m += 64) {
    float s = P.rob[m];
    for (int j = 0; j < NCAT; ++j) s = fmaf(P.lro[b * NCAT + j], P.roW[m * NCAT + j], s);
    enc[m] = fmaxf(s, 0.f);
  }
  __syncthreads();
  for (int n = 0; n < NCAT; ++n) {
    const float* __restrict__ wr = P.ruW + n * 768;
    float s = 0.f;
    for (int k = t; k < 256; k += 64) {
      s = fmaf(bf2f(hvu[k]), wr[k], s);
      s = fmaf(bf2f(hvo[k]), wr[256 + k], s);
      s = fmaf(enc[k],       wr[512 + k], s);
    }
    for (int off = 32; off; off >>= 1) s += __shfl_down(s, off, 64);
    if (t == 0) dec[n] = s + P.rub[n];
  }
  __syncthreads();
  if (t == 0) {
    float M = dec[0];
    for (int j = 1; j < NCAT; ++j) M = fmaxf(M, dec[j]);
    float Ssum = 0.f;
    for (int j = 0; j < NCAT; ++j) Ssum += expf(dec[j] - M);
    const float lse = M + logf(Ssum);
    float neg = 0.f, kl = 0.f;
    for (int j = 0; j < NCAT; ++j) {
      const float lp = dec[j] - lse;
      const float q  = P.lru[b * NCAT + j];
      neg -= q * lp;
      kl  += q * (logf(q) - lp);
    }
    P.out[b] = neg;
    atomicAdd(&P.out[64], kl * 1.4426950408889634f * (1.f / 64.f));
  }
}

extern "C" void kernel_launch(void* const* d_in, const int* in_sizes, int n_in,
                              void* d_out, int out_size, void* d_ws, size_t ws_size,
                              hipStream_t stream) {
  Params P;
  P.ivu = (const int*)d_in[0];
  P.ivo = (const int*)d_in[1];
  P.lro = (const float*)d_in[2];
  if (in_sizes[3] >= in_sizes[4]) { P.VE = (const float*)d_in[3]; P.lru = (const float*)d_in[4]; }
  else                            { P.VE = (const float*)d_in[4]; P.lru = (const float*)d_in[3]; }
  // inst: 0 = vu-L0, 1 = vo-L0, 2 = vu-L1, 3 = vo-L1
  P.W[0][0] = (const float*)d_in[5];  P.W[0][1] = (const float*)d_in[6];
  P.b0[0]   = (const float*)d_in[7];  P.b1[0]   = (const float*)d_in[8];
  P.W[2][0] = (const float*)d_in[9];  P.W[2][1] = (const float*)d_in[10];
  P.b0[2]   = (const float*)d_in[11]; P.b1[2]   = (const float*)d_in[12];
  P.W[1][0] = (const float*)d_in[13]; P.W[1][1] = (const float*)d_in[14];
  P.b0[1]   = (const float*)d_in[15]; P.b1[1]   = (const float*)d_in[16];
  P.W[3][0] = (const float*)d_in[17]; P.W[3][1] = (const float*)d_in[18];
  P.b0[3]   = (const float*)d_in[19]; P.b1[3]   = (const float*)d_in[20];
  P.roW = (const float*)d_in[21]; P.rob = (const float*)d_in[22];
  P.ruW = (const float*)d_in[23]; P.rub = (const float*)d_in[24];
  P.ws  = (float*)d_ws;
  P.out = (float*)d_out;

  // zero flag regions (H flags + G-tile flags) and the KL accumulator
  hipMemsetAsync((char*)d_ws + FLG_OFF, 0, 16384, stream);
  hipMemsetAsync((char*)d_out + 64 * sizeof(float), 0, sizeof(float), stream);

  lstm_all<<<dim3(3264), dim3(256), 0, stream>>>(P);
  head_kernel<<<dim3(64), dim3(64), 0, stream>>>(P);
}

// Round 9
// 606.280 us; speedup vs baseline: 2.2009x; 1.0486x over previous
//
#include <hip/hip_runtime.h>
#include <math.h>

#define S_LEN 100
#define NCAT  18
#define HS    516   // hstage row stride in shorts
#define WSTR  520   // Wlds row stride in shorts
#define FLG_OFF  262144   // 32 slots x 16 B per lstm group (1 KB total)
#define GFLG_OFF 263168   // 3200 u32 per-tile ready flags (12.8 KB)
#define G_OFF    524288   // bf16 layer-0 gate partials: 3200 tiles * 8 KB

typedef __attribute__((ext_vector_type(8)))  short  short8;
typedef __attribute__((ext_vector_type(16))) float  floatx16;

#define AT_LOADU(p)   __hip_atomic_load((p), __ATOMIC_RELAXED, __HIP_MEMORY_SCOPE_AGENT)
#define AT_STORE(p,v) __hip_atomic_store((p),(v), __ATOMIC_RELAXED, __HIP_MEMORY_SCOPE_AGENT)

// ws byte layout:
//   H0[lstm][buf]: bf16 [64 b][256 k] at (lstm*2+buf)*32768         (0..131071)
//   H1[lstm][buf]: same              at 131072 + (lstm*2+buf)*32768  (..262143)
//   flags: FLG_OFF; G-tile flags: GFLG_OFF; G data (bf16): G_OFF.
// Fused grid: blocks 0..63 = lstm lockstep + fused head; blocks 64..3263 =
// gate0 tiles. gate0 swizzle: k = xcd + 128*m + 8*wg, p = xcd+8m, t = p>>1,
// inst = p&1  => all 16 tiles of one (inst,t) share an XCD (VE L2 locality)
// and dispatch order stays t-major. Producer->consumer per tile via
// store -> vmcnt-drain -> flag (relaxed agent atomics), same as H exchange.
// Permuted A-row map: tile row tr holds weight row
// R = (tr&3)*256 + wg*16 + jt*8 + (tr>>2) => acc[r] = gate (r&3),
// dim wg*16 + jt*8 + 2*(r>>2) + half, batch bt*32+(lane&31). H storage is
// UNPERMUTED [b][dim]; a shfl_xor(32) interleave packs contiguous u64 stores.

struct Params {
  const int* ivu; const int* ivo;
  const float* lro; const float* lru;
  const float* VE;
  const float* W[4][2];
  const float* b0[4]; const float* b1[4];
  const float* roW; const float* rob;
  const float* ruW; const float* rub;
  float* ws; float* out;
};

__device__ __forceinline__ unsigned short f2bf(float f) {
  unsigned u = __builtin_bit_cast(unsigned, f);
  u += 0x7FFFu + ((u >> 16) & 1u);          // RNE
  return (unsigned short)(u >> 16);
}
__device__ __forceinline__ float bf2f(unsigned short h) {
  unsigned u = ((unsigned)h) << 16;
  return __builtin_bit_cast(float, u);
}
__device__ __forceinline__ unsigned long long packbf4(float4 v) {
  return (unsigned long long)f2bf(v.x)
       | ((unsigned long long)f2bf(v.y) << 16)
       | ((unsigned long long)f2bf(v.z) << 32)
       | ((unsigned long long)f2bf(v.w) << 48);
}
__device__ __forceinline__ float sigm(float x) {
  return __builtin_amdgcn_rcpf(1.f + __expf(-x));
}
__device__ __forceinline__ float tanh_f(float x) {  // graceful at +/-inf
  return 1.f - 2.f * __builtin_amdgcn_rcpf(1.f + __expf(2.f * x));
}

// agent-scope load of one bf16 G tile (16 values/thread)
__device__ __forceinline__ floatx16 load_gtile(const char* wsb, int idx, int tid) {
  const unsigned long long* gp =
      (const unsigned long long*)(wsb + G_OFF + (size_t)idx * 8192) + tid * 4;
  floatx16 g;
  #pragma unroll
  for (int j = 0; j < 4; ++j) {
    const unsigned long long u = AT_LOADU(gp + j);
    g[4 * j]     = bf2f((unsigned short)u);
    g[4 * j + 1] = bf2f((unsigned short)(u >> 16));
    g[4 * j + 2] = bf2f((unsigned short)(u >> 32));
    g[4 * j + 3] = bf2f((unsigned short)(u >> 48));
  }
  return g;
}

// ---- gate0 tile: G[inst][t][wg] = x_t @ Wih0^T + b0 + b1 (permuted-row acc
// layout, bf16), published with per-tile ready flag.
__device__ __forceinline__ void gate0_body(const Params& P, int k) {
  char* wsb = (char*)P.ws;
  const int xcd = k & 7;
  const int r0  = k >> 3;
  const int wg  = r0 & 15;
  const int m   = r0 >> 4;
  const int p   = xcd + 8 * m;            // 0..199
  const int t   = p >> 1;
  const int inst = p & 1;
  const int blk = (inst * 100 + t) * 16 + wg;   // G storage index

  const int tid = threadIdx.x, lane = tid & 63, wave = tid >> 6;
  const int jt = wave >> 1, bt = wave & 1, half = lane >> 5;
  const int trow = lane & 31;
  const int R = (trow & 3) * 256 + wg * 16 + jt * 8 + (trow >> 2);
  const int b = bt * 32 + trow;
  const int* __restrict__ idxp = inst ? P.ivo : P.ivu;
  const float* __restrict__ wih = P.W[inst][0] + (size_t)R * 256;
  const float* __restrict__ vr = P.VE + (size_t)idxp[b * S_LEN + t] * 256;

  floatx16 acc;
  #pragma unroll
  for (int rr = 0; rr < 16; ++rr) {
    const int Rr = (rr & 3) * 256 + wg * 16 + jt * 8 + 2 * (rr >> 2) + half;
    acc[rr] = P.b0[inst][Rr] + P.b1[inst][Rr];
  }
  #pragma unroll
  for (int s = 0; s < 16; ++s) {
    float4 a0 = *(const float4*)(wih + s * 16 + half * 8);
    float4 a1 = *(const float4*)(wih + s * 16 + half * 8 + 4);
    float4 e0 = *(const float4*)(vr + s * 16 + half * 8);
    float4 e1 = *(const float4*)(vr + s * 16 + half * 8 + 4);
    union { unsigned long long q[2]; short8 v; } ua, ub;
    ua.q[0] = packbf4(a0); ua.q[1] = packbf4(a1);
    ub.q[0] = packbf4(e0); ub.q[1] = packbf4(e1);
    acc = __builtin_amdgcn_mfma_f32_32x32x16_bf16(ua.v, ub.v, acc, 0, 0, 0);
  }
  // publish: bf16 agent-scope data stores, drain, then flag
  unsigned long long* gd =
      (unsigned long long*)(wsb + G_OFF + (size_t)blk * 8192) + tid * 4;
  #pragma unroll
  for (int j = 0; j < 4; ++j) {
    float4 v;
    v.x = acc[4 * j]; v.y = acc[4 * j + 1];
    v.z = acc[4 * j + 2]; v.w = acc[4 * j + 3];
    AT_STORE(gd + j, packbf4(v));
  }
  __syncthreads();                        // vmcnt(0) drain
  if (tid == 0) AT_STORE((unsigned*)(wsb + GFLG_OFF) + blk, 1u);
}

// Fused kernel. Blocks 0..63: lstm lockstep + head tail. Blocks 64+: gate0.
__global__ __launch_bounds__(256, 1) void lstm_all(Params P) {
  __shared__ short          Wlds[64 * WSTR];    // 66.5 KB bf16 weights
  __shared__ unsigned short hstage[64 * HS];    // 64.5 KB x_t bf16 [b][k]
  __shared__ float          enc[256];           // head scratch
  __shared__ float          hbuf[512];
  __shared__ float          dec[NCAT];

  if (blockIdx.x >= 64) { gate0_body(P, (int)blockIdx.x - 64); return; }

  const int tid  = threadIdx.x;
  const int lane = tid & 63;
  const int wave = tid >> 6;            // 0..3
  const int rbk  = blockIdx.x;
  const int xcd  = rbk & 7, grpi = rbk >> 3;
  const int lstm = xcd >> 2;                        // XCDs 0-3: lstm0, 4-7: lstm1
  const int idx32 = grpi * 4 + (xcd & 3);           // 0..31
  const int layer = idx32 >> 4;
  const int wg    = idx32 & 15;
  const int inst  = layer * 2 + lstm;   // 0=vu-L0 1=vo-L0 2=vu-L1 3=vo-L1
  const int gb    = idx32;              // layer*16+wg

  char* wsb = (char*)P.ws;
  unsigned* arr = (unsigned*)(wsb + FLG_OFF) + lstm * 128;   // 32 slots x 4 dwords

  const int jt = wave >> 1, bt = wave & 1;
  const int half = lane >> 5;
  const int trow = lane & 31;
  const int bl   = bt * 32 + trow;

  // ---- stage weights -> LDS bf16, permuted row map (one time) ----
  {
    const int jrow = tid >> 2;          // 0..63 = jts*32 + tr
    const int q    = tid & 3;
    const int tr   = jrow & 31, jts = jrow >> 5;
    const int R    = (tr & 3) * 256 + wg * 16 + jts * 8 + (tr >> 2);
    const float* wih = P.W[inst][0] + (size_t)R * 256;
    const float* whh = P.W[inst][1] + (size_t)R * 256;
    short* dst = &Wlds[jrow * WSTR];
    if (layer || q < 2) {               // layer 0: only k<256 (Whh)
      #pragma unroll
      for (int k = q * 128; k < q * 128 + 128; k += 8) {
        const float* src = layer ? ((k < 256) ? (wih + k) : (whh + (k - 256)))
                                 : (whh + k);
        float4 v0 = *(const float4*)src;
        float4 v1 = *(const float4*)(src + 4);
        *(unsigned long long*)(dst + k)     = packbf4(v0);
        *(unsigned long long*)(dst + k + 4) = packbf4(v1);
      }
    }
  }
  float bias16[16];
  if (layer) {
    #pragma unroll
    for (int r = 0; r < 16; ++r) {
      const int Rr = (r & 3) * 256 + wg * 16 + jt * 8 + 2 * (r >> 2) + half;
      bias16[r] = P.b0[inst][Rr] + P.b1[inst][Rr];
    }
  }

  // ---- zero own group's H buffers: 128 KB over 32 WGs = 2 u64 per thread ----
  #pragma unroll
  for (int j = 0; j < 2; ++j) {
    const int gi = gb * 512 + tid * 2 + j;
    const int r = gi >> 12, off = gi & 4095;
    char* base = wsb + ((r < 2) ? (size_t)(lstm * 2 + r) * 32768
                                : 131072 + (size_t)(lstm * 2 + r - 2) * 32768);
    AT_STORE((unsigned long long*)base + off, 0ull);
  }
  __syncthreads();                       // vmcnt(0) drain
  if (tid == 0) AT_STORE(arr + gb * 4, 1u);

  const int arow_off = (jt * 32 + trow) * WSTR + half * 8;
  const int brow_off = bl * HS + half * 8;
  const unsigned* __restrict__ gflags = (const unsigned*)(wsb + GFLG_OFF);

  floatx16 gcur;
  if (layer == 0) {                      // wait + load G tile for t=0
    const int gidx = (lstm * 100) * 16 + wg;
    while (AT_LOADU(gflags + gidx) == 0) { }
    gcur = load_gtile(wsb, gidx, tid);
  }
  float c[4] = {0.f, 0.f, 0.f, 0.f};

  for (int t = 0; t <= S_LEN; ++t) {
    // ---- one-hop barrier: wave 0 polls all 32 group slots ----
    if (wave == 0) {
      const unsigned want = (unsigned)(t + 1);
      const unsigned* slot = arr + trow * 4;
      while (!__all(AT_LOADU(slot) >= want)) { }
    }
    __syncthreads();

    const bool active = (layer == 0) ? (t < S_LEN) : (t >= 1);
    if (active) {
      const int cur = t & 1, prv = (t + 1) & 1;

      // ---- stage x_t into LDS [b][HS] bf16 ----
      if (layer == 0) {
        const unsigned long long* s64 =
            (const unsigned long long*)(wsb + (size_t)(lstm * 2 + prv) * 32768);
        unsigned long long v[16];
        #pragma unroll
        for (int j = 0; j < 16; ++j) v[j] = AT_LOADU(s64 + tid + j * 256);
        #pragma unroll
        for (int j = 0; j < 16; ++j) {
          const int i = tid + j * 256, bb = i >> 6, kq = i & 63;
          *(unsigned long long*)&hstage[bb * HS + kq * 4] = v[j];
        }
      } else {
        const unsigned long long* lo =
            (const unsigned long long*)(wsb + (size_t)(lstm * 2 + prv) * 32768);   // y0_{t-1}
        const unsigned long long* hi =
            (const unsigned long long*)(wsb + 131072 + (size_t)(lstm * 2 + cur) * 32768); // h1_{t-1}
        unsigned long long v[32];                    // 32 loads in flight
        #pragma unroll
        for (int j = 0; j < 16; ++j) v[j]      = AT_LOADU(lo + tid + j * 256);
        #pragma unroll
        for (int j = 0; j < 16; ++j) v[16 + j] = AT_LOADU(hi + tid + j * 256);
        #pragma unroll
        for (int j = 0; j < 16; ++j) {
          const int i = tid + j * 256, bb = i >> 6, kq = i & 63;
          *(unsigned long long*)&hstage[bb * HS + kq * 4] = v[j];
        }
        #pragma unroll
        for (int j = 0; j < 16; ++j) {
          const int i = tid + j * 256, bb = i >> 6, kq = i & 63;
          *(unsigned long long*)&hstage[bb * HS + 256 + kq * 4] = v[16 + j];
        }
      }
      __syncthreads();

      // ---- MFMA: two independent accumulator chains, A and B from LDS ----
      floatx16 acc, acc2;
      if (layer == 0) {
        acc = gcur;                       // Wih0 x_t + b, precomputed
        #pragma unroll
        for (int r = 0; r < 16; ++r) acc2[r] = 0.f;
        #pragma unroll
        for (int s = 0; s < 16; s += 2) {
          short8 a0 = *(const short8*)&Wlds[arow_off + s * 16];
          short8 b0 = *(const short8*)&hstage[brow_off + s * 16];
          short8 a1 = *(const short8*)&Wlds[arow_off + (s + 1) * 16];
          short8 b1 = *(const short8*)&hstage[brow_off + (s + 1) * 16];
          acc  = __builtin_amdgcn_mfma_f32_32x32x16_bf16(a0, b0, acc,  0, 0, 0);
          acc2 = __builtin_amdgcn_mfma_f32_32x32x16_bf16(a1, b1, acc2, 0, 0, 0);
        }
      } else {
        #pragma unroll
        for (int r = 0; r < 16; ++r) { acc[r] = bias16[r]; acc2[r] = 0.f; }
        #pragma unroll
        for (int s = 0; s < 32; s += 2) {
          short8 a0 = *(const short8*)&Wlds[arow_off + s * 16];
          short8 b0 = *(const short8*)&hstage[brow_off + s * 16];
          short8 a1 = *(const short8*)&Wlds[arow_off + (s + 1) * 16];
          short8 b1 = *(const short8*)&hstage[brow_off + (s + 1) * 16];
          acc  = __builtin_amdgcn_mfma_f32_32x32x16_bf16(a0, b0, acc,  0, 0, 0);
          acc2 = __builtin_amdgcn_mfma_f32_32x32x16_bf16(a1, b1, acc2, 0, 0, 0);
        }
      }
      #pragma unroll
      for (int r = 0; r < 16; ++r) acc[r] += acc2[r];

      // ---- in-register activations: lane owns 4 gates x 4 dims, b fixed ----
      unsigned long long own = 0ull;
      #pragma unroll
      for (int q = 0; q < 4; ++q) {
        const float ig = sigm(acc[4 * q + 0]);
        const float fg = sigm(acc[4 * q + 1]);
        const float gg = tanh_f(acc[4 * q + 2]);
        const float og = sigm(acc[4 * q + 3]);
        const float cc = fg * c[q] + ig * gg;
        c[q] = cc;
        own |= ((unsigned long long)f2bf(og * tanh_f(cc))) << (16 * q);
      }
      // own holds dims base+2q+half (base = wg*16+jt*8), batch bl. Interleave
      // with partner lane (half^1, same batch) to form contiguous u64.
      {
        const unsigned long long oth =
            (unsigned long long)__shfl_xor((long long)own, 32, 64);
        const unsigned long long A = half ? oth : own;   // even-dim holder
        const unsigned long long B = half ? own : oth;   // odd-dim holder
        const unsigned a32 = half ? (unsigned)(A >> 32) : (unsigned)A;
        const unsigned b32 = half ? (unsigned)(B >> 32) : (unsigned)B;
        const unsigned long long pack =
              (unsigned long long)(a32 & 0xFFFFu)
            | ((unsigned long long)(b32 & 0xFFFFu) << 16)
            | ((unsigned long long)(a32 >> 16) << 32)
            | ((unsigned long long)(b32 >> 16) << 48);
        unsigned long long* hout = (layer == 0)
            ? (unsigned long long*)(wsb + (size_t)(lstm * 2 + cur) * 32768)
            : (unsigned long long*)(wsb + 131072 + (size_t)(lstm * 2 + prv) * 32768);
        AT_STORE(hout + bl * 64 + wg * 4 + jt * 2 + half, pack);
      }
    }
    if (t < S_LEN) {
      __syncthreads();                   // vmcnt(0) drain: h stores IF-visible
      if (tid == 0) AT_STORE(arr + gb * 4, (unsigned)(t + 2));
    }
    // fetch next step's G after own flag store (a miss never delays peers)
    if (layer == 0 && t + 1 < S_LEN) {
      const int gidx = (lstm * 100 + t + 1) * 16 + wg;
      while (AT_LOADU(gflags + gidx) == 0) { }
      gcur = load_gtile(wsb, gidx, tid);
    }
  }

  // ---- publish done, wait for all L1 WGs, then fused head (batch = rbk) ----
  __syncthreads();                       // drain t=100 h stores
  if (tid == 0) AT_STORE(arr + gb * 4, 102u);
  if (wave == 0) {
    const unsigned* fb = (const unsigned*)(wsb + FLG_OFF);
    const unsigned* slot = (trow < 16) ? (fb + (16 + trow) * 4)
                                       : (fb + 128 + (trow) * 4);  // trow-16+16
    while (!__all(AT_LOADU(slot) >= 102u)) { }
  }
  __syncthreads();

  {
    const int bb = rbk;
    {
      float s = P.rob[tid];
      #pragma unroll
      for (int j2 = 0; j2 < NCAT; ++j2)
        s = fmaf(P.lro[bb * NCAT + j2], P.roW[tid * NCAT + j2], s);
      enc[tid] = fmaxf(s, 0.f);
    }
    if (tid < 128) {                     // 128 thr x 1 u64 = full 2x256 bf16
      const unsigned long long* hp = (tid < 64)
          ? ((const unsigned long long*)(wsb + 131072 + 1 * 32768) + bb * 64)
          : ((const unsigned long long*)(wsb + 131072 + 3 * 32768) + bb * 64);
      const unsigned long long hv = AT_LOADU(hp + (tid & 63));
      float* dst = &hbuf[(tid < 64 ? 0 : 256) + (tid & 63) * 4];
      dst[0] = bf2f((unsigned short)hv);
      dst[1] = bf2f((unsigned short)(hv >> 16));
      dst[2] = bf2f((unsigned short)(hv >> 32));
      dst[3] = bf2f((unsigned short)(hv >> 48));
    }
    __syncthreads();
    for (int n = wave; n < NCAT; n += 4) {
      const float* __restrict__ wr = P.ruW + n * 768;
      float s = 0.f;
      #pragma unroll
      for (int jj = 0; jj < 4; ++jj) {
        const int k = lane + 64 * jj;
        s = fmaf(hbuf[k],       wr[k],       s);
        s = fmaf(hbuf[256 + k], wr[256 + k], s);
        s = fmaf(enc[k],        wr[512 + k], s);
      }
      #pragma unroll
      for (int off = 32; off; off >>= 1) s += __shfl_down(s, off, 64);
      if (lane == 0) dec[n] = s + P.rub[n];
    }
    __syncthreads();
    if (tid == 0) {
      float M = dec[0];
      for (int j2 = 1; j2 < NCAT; ++j2) M = fmaxf(M, dec[j2]);
      float Ssum = 0.f;
      for (int j2 = 0; j2 < NCAT; ++j2) Ssum += expf(dec[j2] - M);
      const float lse = M + logf(Ssum);
      float neg = 0.f, kl = 0.f;
      for (int j2 = 0; j2 < NCAT; ++j2) {
        const float lp = dec[j2] - lse;
        const float q  = P.lru[bb * NCAT + j2];
        neg -= q * lp;
        kl  += q * (logf(q) - lp);
      }
      P.out[bb] = neg;
      atomicAdd(&P.out[64], kl * 1.4426950408889634f * (1.f / 64.f));
    }
  }
}

extern "C" void kernel_launch(void* const* d_in, const int* in_sizes, int n_in,
                              void* d_out, int out_size, void* d_ws, size_t ws_size,
                              hipStream_t stream) {
  Params P;
  P.ivu = (const int*)d_in[0];
  P.ivo = (const int*)d_in[1];
  P.lro = (const float*)d_in[2];
  if (in_sizes[3] >= in_sizes[4]) { P.VE = (const float*)d_in[3]; P.lru = (const float*)d_in[4]; }
  else                            { P.VE = (const float*)d_in[4]; P.lru = (const float*)d_in[3]; }
  // inst: 0 = vu-L0, 1 = vo-L0, 2 = vu-L1, 3 = vo-L1
  P.W[0][0] = (const float*)d_in[5];  P.W[0][1] = (const float*)d_in[6];
  P.b0[0]   = (const float*)d_in[7];  P.b1[0]   = (const float*)d_in[8];
  P.W[2][0] = (const float*)d_in[9];  P.W[2][1] = (const float*)d_in[10];
  P.b0[2]   = (const float*)d_in[11]; P.b1[2]   = (const float*)d_in[12];
  P.W[1][0] = (const float*)d_in[13]; P.W[1][1] = (const float*)d_in[14];
  P.b0[1]   = (const float*)d_in[15]; P.b1[1]   = (const float*)d_in[16];
  P.W[3][0] = (const float*)d_in[17]; P.W[3][1] = (const float*)d_in[18];
  P.b0[3]   = (const float*)d_in[19]; P.b1[3]   = (const float*)d_in[20];
  P.roW = (const float*)d_in[21]; P.rob = (const float*)d_in[22];
  P.ruW = (const float*)d_in[23]; P.rub = (const float*)d_in[24];
  P.ws  = (float*)d_ws;
  P.out = (float*)d_out;

  // zero flag regions (H flags + G-tile flags) and the KL accumulator
  hipMemsetAsync((char*)d_ws + FLG_OFF, 0, 16384, stream);
  hipMemsetAsync((char*)d_out + 64 * sizeof(float), 0, sizeof(float), stream);

  lstm_all<<<dim3(3264), dim3(256), 0, stream>>>(P);
}